// Round 7
// baseline (171.177 us; speedup 1.0000x reference)
//
#include <hip/hip_runtime.h>
#include <stdint.h>

// ---------- types ----------
typedef __bf16 bf16x8 __attribute__((ext_vector_type(8)));
typedef float f32x4 __attribute__((ext_vector_type(4)));
typedef float float4v __attribute__((ext_vector_type(4)));
typedef unsigned short u16x8 __attribute__((ext_vector_type(8)));

// round-to-nearest-even fp32 -> bf16
__device__ __forceinline__ unsigned short f2bf(float f) {
    unsigned u = __float_as_uint(f);
    u += 0x7fffu + ((u >> 16) & 1u);
    return (unsigned short)(u >> 16);
}

// fast stable softplus: max(x,0) + log(1+exp(-|x|))
__device__ __forceinline__ float softplus(float x) {
    return fmaxf(x, 0.0f) + __logf(1.0f + __expf(-fabsf(x)));
}

// async global->LDS, 16B per lane (gfx950). LDS dest must be wave-uniform
// base + lane*16 (lane-ordered, contiguous).
__device__ __forceinline__ void gl_lds16(const void* gptr, void* lptr) {
    auto g = reinterpret_cast<const __attribute__((address_space(1))) void*>(
        reinterpret_cast<uintptr_t>(gptr));
    auto l = reinterpret_cast<__attribute__((address_space(3))) void*>(
        reinterpret_cast<uintptr_t>(lptr));
    __builtin_amdgcn_global_load_lds(g, l, 16, 0, 0);
}

// ---------- fused prep: input f32->bf16  AND  w = mu + softplus(rho)*eps ----
__global__ void prep_kernel(const float* __restrict__ in,
                            const float* __restrict__ mu,
                            const float* __restrict__ rho,
                            const float* __restrict__ eps,
                            unsigned short* __restrict__ in_bf,
                            unsigned short* __restrict__ w_bf,
                            int nIn8, int nW8) {
    int i = blockIdx.x * blockDim.x + threadIdx.x;
    if (i < nIn8) {
        const float4v* p = (const float4v*)in + (size_t)i * 2;
        float4v a = p[0], b = p[1];
        u16x8 r;
        r[0] = f2bf(a[0]); r[1] = f2bf(a[1]); r[2] = f2bf(a[2]); r[3] = f2bf(a[3]);
        r[4] = f2bf(b[0]); r[5] = f2bf(b[1]); r[6] = f2bf(b[2]); r[7] = f2bf(b[3]);
        ((u16x8*)in_bf)[i] = r;
    } else {
        int j = i - nIn8;
        if (j >= nW8) return;
        const float4v* pm = (const float4v*)mu  + (size_t)j * 2;
        const float4v* pr = (const float4v*)rho + (size_t)j * 2;
        const float4v* pe = (const float4v*)eps + (size_t)j * 2;
        float4v m0 = pm[0], m1 = pm[1];
        float4v r0 = pr[0], r1 = pr[1];
        float4v e0 = pe[0], e1 = pe[1];
        u16x8 r;
        r[0] = f2bf(m0[0] + softplus(r0[0]) * e0[0]);
        r[1] = f2bf(m0[1] + softplus(r0[1]) * e0[1]);
        r[2] = f2bf(m0[2] + softplus(r0[2]) * e0[2]);
        r[3] = f2bf(m0[3] + softplus(r0[3]) * e0[3]);
        r[4] = f2bf(m1[0] + softplus(r1[0]) * e1[0]);
        r[5] = f2bf(m1[1] + softplus(r1[1]) * e1[1]);
        r[6] = f2bf(m1[2] + softplus(r1[2]) * e1[2]);
        r[7] = f2bf(m1[3] + softplus(r1[3]) * e1[3]);
        ((u16x8*)w_bf)[j] = r;
    }
}

// ---------- GEMM: C[M,N] = A[M,K] * B[N,K]^T + bias, bf16 in / f32 out -----
// R7: R0's PROVEN sync structure (hoist frag reads -> stage next buf ->
// MFMAs -> single __syncthreads drain; 2 blocks/CU cover each other's
// drains) with FIXED GEOMETRY:
//   R6 post-mortem: all ring variants (counted vmcnt, reg-dbuf, 1 barrier,
//   full occupancy) land 48-52us vs R0's 42us -> schedule is not the lever.
//   R0's 64x32 wave tiles re-read A x4 / B x2 = 192 KB LDS reads per CU per
//   1241 MFMA-cycles: LDS pipe >= MFMA pipe (geometry-bound, schedule-proof).
//   This round: BM=256 x BN=128 tile, 8 waves of 64x64 (A-rereads x2, B x4
//   -> per barrier per wave: 16 MFMA (same as R0), 8 ds_read_b128 (-33%),
//   3 stage ops (-25%)). LDS 2 x 24 KB = 48 KB static -> 2 blocks/CU ->
//   16 waves/CU (= R0 occupancy). Grid 16x16 = 256 blocks = 1 full set.
//   - KC=32 XOR swizzle (R4-verified 0 conflicts): key=(row>>1)&3 on the
//     global SOURCE k-group (LDS dest linear per gl_lds requirement), same
//     key on ds_read offsets. Key invariant under +16/+64/+128 row shifts.
//   - launch_bounds(512,4): cap VGPR at 128 for 4 waves/SIMD (acc 64 +
//     small live frag window; R6 measured 52 with half this acc).
//   - s_setprio(1) around the MFMA cluster (T5, cheap).
#define BM 256
#define BN 128
#define KC 32
#define BUF_U 12288   // ushorts per buffer: A 256*32 (8192) + B 128*32 (4096)

__global__ __launch_bounds__(512, 4)
void gemm_bt_kernel(const unsigned short* __restrict__ A,   // [M,K] bf16
                    const unsigned short* __restrict__ B,   // [N,K] bf16
                    const float* __restrict__ bias,         // [N]
                    float* __restrict__ C,                  // [M,N] f32
                    int M, int N, int K) {
    __shared__ unsigned short lds[2][BUF_U];   // 48 KB

    const int t      = threadIdx.x;
    const int lane   = t & 63;
    const int wave   = t >> 6;          // 0..7
    const int lane16 = lane & 15;
    const int quad   = lane >> 4;       // 0..3
    const int wm     = wave & 3;        // wave row: 0..3 (64 rows each)
    const int wn     = wave >> 2;       // wave col: 0..1 (64 cols each)

    const int m0 = blockIdx.y * BM;
    const int n0 = blockIdx.x * BN;

    // staging: buffer = A[256][32] + B[128][32] = 1536 x 16B, 512 thr ->
    // 2 A-pieces + 1 B-piece each. LDS dest linear (lane-ordered); global
    // SOURCE k-group carries the swizzle: slot (row,ps) holds kg ps^((row>>1)&3).
    const int r   = t >> 2;                       // 0..127
    const int key = (t >> 3) & 3;                 // (r>>1)&3; same for r+128
    const int kgs = ((t & 3) ^ key) * 8;          // swizzled k-elem offset

    const unsigned short* aP0 = A + (size_t)(m0 + r)       * K + kgs;
    const unsigned short* aP1 = A + (size_t)(m0 + 128 + r) * K + kgs;
    const unsigned short* bP  = B + (size_t)(n0 + r)       * K + kgs;

    f32x4 acc[4][4] = {};

    auto stage = [&](int buf, int it) {
        const int k0 = it * KC;
        gl_lds16(aP0 + k0, &lds[buf][t * 8]);
        gl_lds16(aP1 + k0, &lds[buf][4096 + t * 8]);
        gl_lds16(bP  + k0, &lds[buf][8192 + t * 8]);
    };

    // fragment read offsets (ushort idx), swizzled: phys_kg = quad ^ sw,
    // sw = (row>>1)&3 = (lane16>>1)&3 (invariant under wm*64 / mi*16).
    const int sw = (lane16 >> 1) & 3;
    const int ra = (wm * 64 + lane16) * KC + ((quad ^ sw) * 8);
    const int rb = 8192 + (wn * 64 + lane16) * KC + ((quad ^ sw) * 8);

    const int nit = K / KC;       // 64 (even)
    stage(0, 0);
    __syncthreads();              // drain prologue staging

    auto body = [&](int cur, int it) {
        const unsigned short* la = lds[cur];
        // (1) hoist ALL fragment reads from current buffer
        bf16x8 af[4], bfr[4];
#pragma unroll
        for (int mi = 0; mi < 4; ++mi)
            af[mi] = *(const bf16x8*)(la + ra + mi * 16 * KC);
#pragma unroll
        for (int ni = 0; ni < 4; ++ni)
            bfr[ni] = *(const bf16x8*)(la + rb + ni * 16 * KC);
        // (2) async-stage NEXT chunk into the other buffer
        if (it + 1 < nit) stage(cur ^ 1, it + 1);
        // (3) MFMAs -- vmcnt drain at the barrier lands after these
        __builtin_amdgcn_s_setprio(1);
#pragma unroll
        for (int mi = 0; mi < 4; ++mi)
#pragma unroll
            for (int ni = 0; ni < 4; ++ni)
                acc[mi][ni] = __builtin_amdgcn_mfma_f32_16x16x32_bf16(
                    af[mi], bfr[ni], acc[mi][ni], 0, 0, 0);
        __builtin_amdgcn_s_setprio(0);
        // (4) single barrier: staging drained AND current buffer released
        __syncthreads();
    };

    for (int it = 0; it < nit; it += 2) {
        body(0, it);
        body(1, it + 1);
    }

    // epilogue: C/D layout col=lane&15, row=quad*4+reg (m89-verified)
    float bv[4];
#pragma unroll
    for (int ni = 0; ni < 4; ++ni)
        bv[ni] = bias[n0 + wn * 64 + ni * 16 + lane16];

#pragma unroll
    for (int mi = 0; mi < 4; ++mi) {
        const int rbase = m0 + wm * 64 + mi * 16 + quad * 4;
#pragma unroll
        for (int ni = 0; ni < 4; ++ni) {
            const int col = n0 + wn * 64 + ni * 16 + lane16;
#pragma unroll
            for (int rr = 0; rr < 4; ++rr)
                C[(size_t)(rbase + rr) * N + col] = acc[mi][ni][rr] + bv[ni];
        }
    }
}

extern "C" void kernel_launch(void* const* d_in, const int* in_sizes, int n_in,
                              void* d_out, int out_size, void* d_ws, size_t ws_size,
                              hipStream_t stream) {
    const float* input = (const float*)d_in[0];
    const float* mu    = (const float*)d_in[1];
    const float* rho   = (const float*)d_in[2];
    const float* eps   = (const float*)d_in[3];
    const float* bias  = (const float*)d_in[4];
    float* out = (float*)d_out;

    const int OUT = in_sizes[4];              // 2048
    const int IN  = in_sizes[1] / OUT;        // 2048
    const int M   = in_sizes[0] / IN;         // 4096

    unsigned short* in_bf = (unsigned short*)d_ws;                 // M*IN bf16
    unsigned short* w_bf  = in_bf + (size_t)M * IN;                // OUT*IN bf16

    const int nIn8 = (M * IN) / 8;
    const int nW8  = (OUT * IN) / 8;
    prep_kernel<<<dim3((nIn8 + nW8 + 255) / 256), 256, 0, stream>>>(
        input, mu, rho, eps, in_bf, w_bf, nIn8, nW8);

    gemm_bt_kernel<<<dim3(OUT / BN, M / BM), 512, 0, stream>>>(
        in_bf, w_bf, bias, out, M, OUT, IN);
}

// Round 8
// 159.322 us; speedup vs baseline: 1.0744x; 1.0744x over previous
//
#include <hip/hip_runtime.h>
#include <stdint.h>

// ---------- types ----------
typedef __bf16 bf16x8 __attribute__((ext_vector_type(8)));
typedef float f32x4 __attribute__((ext_vector_type(4)));
typedef float float4v __attribute__((ext_vector_type(4)));
typedef unsigned short u16x8 __attribute__((ext_vector_type(8)));

// round-to-nearest-even fp32 -> bf16
__device__ __forceinline__ unsigned short f2bf(float f) {
    unsigned u = __float_as_uint(f);
    u += 0x7fffu + ((u >> 16) & 1u);
    return (unsigned short)(u >> 16);
}

// fast stable softplus: max(x,0) + log(1+exp(-|x|))
__device__ __forceinline__ float softplus(float x) {
    return fmaxf(x, 0.0f) + __logf(1.0f + __expf(-fabsf(x)));
}

// async global->LDS, 16B per lane (gfx950). LDS dest must be wave-uniform
// base + lane*16 (lane-ordered, contiguous).
__device__ __forceinline__ void gl_lds16(const void* gptr, void* lptr) {
    auto g = reinterpret_cast<const __attribute__((address_space(1))) void*>(
        reinterpret_cast<uintptr_t>(gptr));
    auto l = reinterpret_cast<__attribute__((address_space(3))) void*>(
        reinterpret_cast<uintptr_t>(lptr));
    __builtin_amdgcn_global_load_lds(g, l, 16, 0, 0);
}

// ---------- fused prep: input f32->bf16  AND  w = mu + softplus(rho)*eps ----
__global__ void prep_kernel(const float* __restrict__ in,
                            const float* __restrict__ mu,
                            const float* __restrict__ rho,
                            const float* __restrict__ eps,
                            unsigned short* __restrict__ in_bf,
                            unsigned short* __restrict__ w_bf,
                            int nIn8, int nW8) {
    int i = blockIdx.x * blockDim.x + threadIdx.x;
    if (i < nIn8) {
        const float4v* p = (const float4v*)in + (size_t)i * 2;
        float4v a = p[0], b = p[1];
        u16x8 r;
        r[0] = f2bf(a[0]); r[1] = f2bf(a[1]); r[2] = f2bf(a[2]); r[3] = f2bf(a[3]);
        r[4] = f2bf(b[0]); r[5] = f2bf(b[1]); r[6] = f2bf(b[2]); r[7] = f2bf(b[3]);
        ((u16x8*)in_bf)[i] = r;
    } else {
        int j = i - nIn8;
        if (j >= nW8) return;
        const float4v* pm = (const float4v*)mu  + (size_t)j * 2;
        const float4v* pr = (const float4v*)rho + (size_t)j * 2;
        const float4v* pe = (const float4v*)eps + (size_t)j * 2;
        float4v m0 = pm[0], m1 = pm[1];
        float4v r0 = pr[0], r1 = pr[1];
        float4v e0 = pe[0], e1 = pe[1];
        u16x8 r;
        r[0] = f2bf(m0[0] + softplus(r0[0]) * e0[0]);
        r[1] = f2bf(m0[1] + softplus(r0[1]) * e0[1]);
        r[2] = f2bf(m0[2] + softplus(r0[2]) * e0[2]);
        r[3] = f2bf(m0[3] + softplus(r0[3]) * e0[3]);
        r[4] = f2bf(m1[0] + softplus(r1[0]) * e1[0]);
        r[5] = f2bf(m1[1] + softplus(r1[1]) * e1[1]);
        r[6] = f2bf(m1[2] + softplus(r1[2]) * e1[2]);
        r[7] = f2bf(m1[3] + softplus(r1[3]) * e1[3]);
        ((u16x8*)w_bf)[j] = r;
    }
}

// ---------- GEMM: C[M,N] = A[M,K] * B[N,K]^T + bias, bf16 in / f32 out -----
// R8: R0's EXACT skeleton (128x128 tile, 512 thr, BK=64 double-buffer,
// hoist frag reads -> async-stage next -> MFMAs -> single __syncthreads;
// grid 512 = 2 blocks/CU covering each other's barrier drains) with
// WAVE-LEVEL SPLIT-K geometry:
//   Cycle accounting across R0-R7: per CU-window MFMA = 1030 cy; LDS reads
//   at R0's 64x32 wave tiles = 196 KB = 1750 cy -> LDS pipe 1.7x over-
//   subscribed; no schedule can fix geometry. 8 waves = 2x2 spatial
//   (64x64 out each) x 2 K-halves (KC=32 each): per wave per window
//   8 ds_read_b128 (was 12) + 16 MFMA (same barrier amortization).
//   LDS/CU-window: 128 KB = 1150 cy ~= MFMA 1030 cy -> balanced.
//   - Staging + XOR swizzle byte-identical to R0 (0 conflicts verified):
//     phys k-group p at row holds logical p^(row&7); reads use
//     sw = lane16&7, logical kg = kh*4+quad.
//   - Epilogue: K-half-1 waves dump acc to LDS (row stride 66 floats ->
//     quad bank offsets {0,8,16,24}+lane16 = uniform 2-way = free, m136),
//     K-half-0 waves read+add+bias+store. 2 phases (2 waves each) to fit
//     the 64 KB LDS (2 x 4224 floats = 33.8 KB per phase).
#define BM 128
#define BN 128
#define BK 64
#define EX_S 66            // epilogue exchange row stride (floats)

__global__ __launch_bounds__(512, 4)
void gemm_bt_kernel(const unsigned short* __restrict__ A,   // [M,K] bf16
                    const unsigned short* __restrict__ B,   // [N,K] bf16
                    const float* __restrict__ bias,         // [N]
                    float* __restrict__ C,                  // [M,N] f32
                    int M, int N, int K) {
    __shared__ unsigned short smem[32768];      // 64 KB total
    // layout: A buffers [0,16384) : buf*8192 ; B buffers [16384,32768)
    unsigned short* lds_a0 = smem;
    unsigned short* lds_b0 = smem + 16384;

    const int t      = threadIdx.x;
    const int lane   = t & 63;
    const int wave   = t >> 6;          // 0..7
    const int lane16 = lane & 15;
    const int quad   = lane >> 4;       // 0..3
    const int wq     = wave & 3;        // spatial quadrant 0..3
    const int kh     = wave >> 2;       // K-half 0/1
    const int wm     = wq & 1;          // wave row: 0..1 (64 rows each)
    const int wn     = wq >> 1;         // wave col: 0..1 (64 cols each)

    const int m0 = blockIdx.y * BM;
    const int n0 = blockIdx.x * BN;

    // staging: 1024 16B-chunks per tile, 512 threads -> 2 chunks each.
    // chunk c -> LDS slot c (row = c>>3, pkg = c&7); global kg = pkg ^ (row&7)
    const int r1   = t >> 3;                 // rows 0..63
    const int pkg1 = t & 7;
    const int g1   = (pkg1 ^ (r1 & 7)) * 8;
    const int r2   = r1 + 64;                // rows 64..127 (r2&7 == r1&7)
    const int g2   = (pkg1 ^ (r2 & 7)) * 8;

    const unsigned short* Ab = A + (size_t)m0 * K;
    const unsigned short* Bb = B + (size_t)n0 * K;

    f32x4 acc[4][4] = {};

    auto stage = [&](int buf, int k0) {
        gl_lds16(Ab + (size_t)r1 * K + k0 + g1, lds_a0 + buf * 8192 + t * 8);
        gl_lds16(Ab + (size_t)r2 * K + k0 + g2, lds_a0 + buf * 8192 + 4096 + t * 8);
        gl_lds16(Bb + (size_t)r1 * K + k0 + g1, lds_b0 + buf * 8192 + t * 8);
        gl_lds16(Bb + (size_t)r2 * K + k0 + g2, lds_b0 + buf * 8192 + 4096 + t * 8);
    };

    // fragment read offsets: row = (wm|wn)*64 + base + lane16, logical
    // k-group = kh*4 + quad, phys = logical ^ (row&7) = logical ^ (lane16&7)
    const int sw = lane16 & 7;
    const int raBase = (wm * 64 + lane16) * BK + (((kh * 4 + quad) ^ sw) * 8);
    const int rbBase = (wn * 64 + lane16) * BK + (((kh * 4 + quad) ^ sw) * 8);

    const int nit = K / BK;       // 32 (even)
    stage(0, 0);
    __syncthreads();              // drain prologue staging

    auto body = [&](int cur, int it) {
        const unsigned short* la = lds_a0 + cur * 8192;
        const unsigned short* lb = lds_b0 + cur * 8192;
        // (1) hoist ALL fragment reads for this wave's K-half
        bf16x8 af[4], bfr[4];
#pragma unroll
        for (int mi = 0; mi < 4; ++mi)
            af[mi] = *(const bf16x8*)(la + raBase + mi * 16 * BK);
#pragma unroll
        for (int ni = 0; ni < 4; ++ni)
            bfr[ni] = *(const bf16x8*)(lb + rbBase + ni * 16 * BK);
        // (2) async-stage NEXT buffer (no alias with reads)
        if (it + 1 < nit) stage(cur ^ 1, (it + 1) * BK);
        // (3) MFMAs -- vmcnt drain at the barrier lands after these
#pragma unroll
        for (int mi = 0; mi < 4; ++mi)
#pragma unroll
            for (int ni = 0; ni < 4; ++ni)
                acc[mi][ni] = __builtin_amdgcn_mfma_f32_16x16x32_bf16(
                    af[mi], bfr[ni], acc[mi][ni], 0, 0, 0);
        // (4) single barrier: next-staging drained AND current buffer released
        __syncthreads();
    };

    for (int it = 0; it < nit; it += 2) {
        body(0, it);
        body(1, it + 1);
    }
    // last body ended with __syncthreads: buffers free, all MFMAs done.

    // ---- cross-K-half reduction through LDS, 2 phases of 2 quadrants ----
    float* fs = (float*)smem;     // 16384 floats available
#pragma unroll
    for (int ph = 0; ph < 2; ++ph) {
        const bool mine = (wq >> 1) == ph;      // wq in {2ph, 2ph+1}
        const int rbase0 = (wq & 1) * (64 * EX_S);
        if (kh == 1 && mine) {
#pragma unroll
            for (int mi = 0; mi < 4; ++mi)
#pragma unroll
                for (int ni = 0; ni < 4; ++ni)
#pragma unroll
                    for (int rr = 0; rr < 4; ++rr)
                        fs[rbase0 + (mi * 16 + quad * 4 + rr) * EX_S +
                           ni * 16 + lane16] = acc[mi][ni][rr];
        }
        __syncthreads();
        if (kh == 0 && mine) {
#pragma unroll
            for (int mi = 0; mi < 4; ++mi)
#pragma unroll
                for (int ni = 0; ni < 4; ++ni)
#pragma unroll
                    for (int rr = 0; rr < 4; ++rr)
                        acc[mi][ni][rr] += fs[rbase0 +
                            (mi * 16 + quad * 4 + rr) * EX_S + ni * 16 + lane16];
        }
        __syncthreads();
    }

    if (kh != 0) return;          // upper waves done (all barriers passed)

    // epilogue: C/D layout col=lane&15, row=quad*4+reg (m89-verified)
    float bv[4];
#pragma unroll
    for (int ni = 0; ni < 4; ++ni)
        bv[ni] = bias[n0 + wn * 64 + ni * 16 + lane16];

#pragma unroll
    for (int mi = 0; mi < 4; ++mi) {
        const int rbase = m0 + wm * 64 + mi * 16 + quad * 4;
#pragma unroll
        for (int ni = 0; ni < 4; ++ni) {
            const int col = n0 + wn * 64 + ni * 16 + lane16;
#pragma unroll
            for (int rr = 0; rr < 4; ++rr)
                C[(size_t)(rbase + rr) * N + col] = acc[mi][ni][rr] + bv[ni];
        }
    }
}

extern "C" void kernel_launch(void* const* d_in, const int* in_sizes, int n_in,
                              void* d_out, int out_size, void* d_ws, size_t ws_size,
                              hipStream_t stream) {
    const float* input = (const float*)d_in[0];
    const float* mu    = (const float*)d_in[1];
    const float* rho   = (const float*)d_in[2];
    const float* eps   = (const float*)d_in[3];
    const float* bias  = (const float*)d_in[4];
    float* out = (float*)d_out;

    const int OUT = in_sizes[4];              // 2048
    const int IN  = in_sizes[1] / OUT;        // 2048
    const int M   = in_sizes[0] / IN;         // 4096

    unsigned short* in_bf = (unsigned short*)d_ws;                 // M*IN bf16
    unsigned short* w_bf  = in_bf + (size_t)M * IN;                // OUT*IN bf16

    const int nIn8 = (M * IN) / 8;
    const int nW8  = (OUT * IN) / 8;
    prep_kernel<<<dim3((nIn8 + nW8 + 255) / 256), 256, 0, stream>>>(
        input, mu, rho, eps, in_bf, w_bf, nIn8, nW8);

    gemm_bt_kernel<<<dim3(OUT / BN, M / BM), 512, 0, stream>>>(
        in_bf, w_bf, bias, out, M, OUT, IN);
}